// Round 1
// baseline (6213.301 us; speedup 1.0000x reference)
//
#include <hip/hip_runtime.h>
#include <stdint.h>

// ST_BLOCK: Chebyshev graph-conv LSTM on MI355X.
// Strategy: fp32 emulated via bf16 hi/lo split + 3-pass MFMA (16x16x32_bf16).
// Per step: g1 = tem@adjT ; g2 = 2*g1@adjT - tem ; fea = Wcat@[tem;g1;g2] + b ; LSTM update.

#define Bb   16
#define CIN  32
#define COUT 64
#define Nn   1024
#define Tt   64
#define Ff   96     // CIN+COUT
#define G4   256    // 4*COUT
#define KJ   288    // Ff*3

typedef unsigned short u16;
typedef short short8 __attribute__((ext_vector_type(8)));
typedef float f32x4 __attribute__((ext_vector_type(4)));

static __device__ __forceinline__ u16 f2bf(float f) {
    union { float f; uint32_t u; } v; v.f = f;
    uint32_t r = v.u + 0x7FFFu + ((v.u >> 16) & 1u);
    return (u16)(r >> 16);
}
static __device__ __forceinline__ float bf2f(u16 h) {
    union { uint32_t u; float f; } v; v.u = ((uint32_t)h) << 16;
    return v.f;
}
static __device__ __forceinline__ float sigm(float x) { return 1.0f / (1.0f + expf(-x)); }

// ---------------- diagnostics ----------------
__global__ void k_fill(float* out, int n, float v) {
    int i = blockIdx.x * 256 + threadIdx.x;
    if (i < n) out[i] = v;
}

// ---------------- P0: adj split (layout [q][n], no transpose needed) ----------------
__global__ __launch_bounds__(256) void k_adj_split(const float* __restrict__ adj,
                                                   u16* __restrict__ hi, u16* __restrict__ lo) {
    int i = blockIdx.x * 256 + threadIdx.x;
    float v = adj[i];
    u16 h = f2bf(v);
    hi[i] = h; lo[i] = f2bf(v - bf2f(h));
}

// ---------------- P2: W reorder+split: Wcat[o][k*96+f] = W[o][f*3+k] ----------------
__global__ __launch_bounds__(256) void k_w_split(const float* __restrict__ W,
                                                 u16* __restrict__ hi, u16* __restrict__ lo) {
    int idx = blockIdx.x * 256 + threadIdx.x;   // < 256*288
    int o = idx / KJ, j = idx - o * KJ;
    int k = j / Ff, f = j - k * Ff;
    float v = W[(size_t)o * KJ + f * 3 + k];
    u16 h = f2bf(v);
    hi[idx] = h; lo[idx] = f2bf(v - bf2f(h));
}

// ---------------- P1: x (B,CIN,N,T) -> xs (T,B,CIN,N) split ----------------
__global__ __launch_bounds__(256) void k_x_split(const float* __restrict__ x,
                                                 u16* __restrict__ xs_hi, u16* __restrict__ xs_lo) {
    __shared__ float tile[64][65];
    int n0 = blockIdx.x * 64;          // 16 tiles over N
    int bc = blockIdx.y;               // b*CIN + ch, 0..511
    const float* src = x + (size_t)bc * Nn * Tt;
    int tid = threadIdx.x;
    #pragma unroll
    for (int i = 0; i < 16; i++) {
        int lin = i * 256 + tid;
        int nl = lin >> 6, tl = lin & 63;
        tile[nl][tl] = src[(size_t)(n0 + nl) * Tt + tl];
    }
    __syncthreads();
    int b = bc >> 5, ch = bc & 31;
    #pragma unroll
    for (int i = 0; i < 16; i++) {
        int lin = i * 256 + tid;
        int tl = lin >> 6, nl = lin & 63;
        float v = tile[nl][tl];
        u16 h = f2bf(v);
        size_t off = (((size_t)tl * Bb + b) * CIN + ch) * Nn + n0 + nl;
        xs_hi[off] = h; xs_lo[off] = f2bf(v - bf2f(h));
    }
}

// ---------------- K1: g1 = tem @ adjT  (M=1536, N=1024, K=1024) ----------------
__global__ __launch_bounds__(256) void k_g1(
    int t,
    const u16* __restrict__ xs_hi, const u16* __restrict__ xs_lo,
    const u16* __restrict__ h_hi,  const u16* __restrict__ h_lo,
    const u16* __restrict__ adj_hi, const u16* __restrict__ adj_lo,
    u16* __restrict__ g1_hi, u16* __restrict__ g1_lo)
{
    __shared__ u16 Ah[64][40], Al[64][40], Bh[64][40], Bl[64][40];
    const int tid = threadIdx.x, lane = tid & 63, w = tid >> 6;
    const int wm = (w >> 1) * 32, wn = (w & 1) * 32;
    const int r0 = blockIdx.x * 64, q0 = blockIdx.y * 64;

    const int srow = tid >> 2, scol = (tid & 3) * 8;
    int r = r0 + srow;
    int b = r / Ff, fr = r - b * Ff;
    const u16 *arh, *arl;
    if (fr < CIN) {
        size_t off = ((size_t)((t * Bb + b) * CIN + fr)) * Nn;
        arh = xs_hi + off; arl = xs_lo + off;
    } else {
        size_t off = ((size_t)(b * COUT + fr - CIN)) * Nn;
        arh = h_hi + off; arl = h_lo + off;
    }
    const u16* brh = adj_hi + (size_t)(q0 + srow) * Nn;
    const u16* brl = adj_lo + (size_t)(q0 + srow) * Nn;

    f32x4 acc[2][2];
    #pragma unroll
    for (int i = 0; i < 2; i++)
        #pragma unroll
        for (int j = 0; j < 2; j++) acc[i][j] = (f32x4){0.f, 0.f, 0.f, 0.f};

    for (int k0 = 0; k0 < Nn; k0 += 32) {
        __syncthreads();
        *(short8*)&Ah[srow][scol] = *(const short8*)&arh[k0 + scol];
        *(short8*)&Al[srow][scol] = *(const short8*)&arl[k0 + scol];
        *(short8*)&Bh[srow][scol] = *(const short8*)&brh[k0 + scol];
        *(short8*)&Bl[srow][scol] = *(const short8*)&brl[k0 + scol];
        __syncthreads();
        const int kb = (lane >> 4) * 8;
        short8 ah[2], al[2], bh[2], bl[2];
        #pragma unroll
        for (int mi = 0; mi < 2; mi++) {
            int row = wm + mi * 16 + (lane & 15);
            ah[mi] = *(const short8*)&Ah[row][kb];
            al[mi] = *(const short8*)&Al[row][kb];
        }
        #pragma unroll
        for (int ni = 0; ni < 2; ni++) {
            int col = wn + ni * 16 + (lane & 15);
            bh[ni] = *(const short8*)&Bh[col][kb];
            bl[ni] = *(const short8*)&Bl[col][kb];
        }
        #pragma unroll
        for (int mi = 0; mi < 2; mi++)
            #pragma unroll
            for (int ni = 0; ni < 2; ni++) {
                acc[mi][ni] = __builtin_amdgcn_mfma_f32_16x16x32_bf16(ah[mi], bh[ni], acc[mi][ni], 0, 0, 0);
                acc[mi][ni] = __builtin_amdgcn_mfma_f32_16x16x32_bf16(al[mi], bh[ni], acc[mi][ni], 0, 0, 0);
                acc[mi][ni] = __builtin_amdgcn_mfma_f32_16x16x32_bf16(ah[mi], bl[ni], acc[mi][ni], 0, 0, 0);
            }
    }
    #pragma unroll
    for (int mi = 0; mi < 2; mi++)
        #pragma unroll
        for (int ni = 0; ni < 2; ni++)
            #pragma unroll
            for (int j = 0; j < 4; j++) {
                int rr = r0 + wm + mi * 16 + (lane >> 4) * 4 + j;
                int qq = q0 + wn + ni * 16 + (lane & 15);
                size_t off = (size_t)rr * Nn + qq;
                float v = acc[mi][ni][j];
                u16 hh = f2bf(v);
                g1_hi[off] = hh; g1_lo[off] = f2bf(v - bf2f(hh));
            }
}

// ---------------- K2: g2 = 2*(g1 @ adjT) - tem ----------------
__global__ __launch_bounds__(256) void k_g2(
    int t,
    const u16* __restrict__ g1_hi, const u16* __restrict__ g1_lo,
    const u16* __restrict__ adj_hi, const u16* __restrict__ adj_lo,
    const u16* __restrict__ xs_hi, const u16* __restrict__ xs_lo,
    const u16* __restrict__ h_hi,  const u16* __restrict__ h_lo,
    u16* __restrict__ g2_hi, u16* __restrict__ g2_lo)
{
    __shared__ u16 Ah[64][40], Al[64][40], Bh[64][40], Bl[64][40];
    const int tid = threadIdx.x, lane = tid & 63, w = tid >> 6;
    const int wm = (w >> 1) * 32, wn = (w & 1) * 32;
    const int r0 = blockIdx.x * 64, q0 = blockIdx.y * 64;

    const int srow = tid >> 2, scol = (tid & 3) * 8;
    int r = r0 + srow;
    const u16* arh = g1_hi + (size_t)r * Nn;
    const u16* arl = g1_lo + (size_t)r * Nn;
    const u16* brh = adj_hi + (size_t)(q0 + srow) * Nn;
    const u16* brl = adj_lo + (size_t)(q0 + srow) * Nn;

    f32x4 acc[2][2];
    #pragma unroll
    for (int i = 0; i < 2; i++)
        #pragma unroll
        for (int j = 0; j < 2; j++) acc[i][j] = (f32x4){0.f, 0.f, 0.f, 0.f};

    for (int k0 = 0; k0 < Nn; k0 += 32) {
        __syncthreads();
        *(short8*)&Ah[srow][scol] = *(const short8*)&arh[k0 + scol];
        *(short8*)&Al[srow][scol] = *(const short8*)&arl[k0 + scol];
        *(short8*)&Bh[srow][scol] = *(const short8*)&brh[k0 + scol];
        *(short8*)&Bl[srow][scol] = *(const short8*)&brl[k0 + scol];
        __syncthreads();
        const int kb = (lane >> 4) * 8;
        short8 ah[2], al[2], bh[2], bl[2];
        #pragma unroll
        for (int mi = 0; mi < 2; mi++) {
            int row = wm + mi * 16 + (lane & 15);
            ah[mi] = *(const short8*)&Ah[row][kb];
            al[mi] = *(const short8*)&Al[row][kb];
        }
        #pragma unroll
        for (int ni = 0; ni < 2; ni++) {
            int col = wn + ni * 16 + (lane & 15);
            bh[ni] = *(const short8*)&Bh[col][kb];
            bl[ni] = *(const short8*)&Bl[col][kb];
        }
        #pragma unroll
        for (int mi = 0; mi < 2; mi++)
            #pragma unroll
            for (int ni = 0; ni < 2; ni++) {
                acc[mi][ni] = __builtin_amdgcn_mfma_f32_16x16x32_bf16(ah[mi], bh[ni], acc[mi][ni], 0, 0, 0);
                acc[mi][ni] = __builtin_amdgcn_mfma_f32_16x16x32_bf16(al[mi], bh[ni], acc[mi][ni], 0, 0, 0);
                acc[mi][ni] = __builtin_amdgcn_mfma_f32_16x16x32_bf16(ah[mi], bl[ni], acc[mi][ni], 0, 0, 0);
            }
    }
    #pragma unroll
    for (int mi = 0; mi < 2; mi++)
        #pragma unroll
        for (int ni = 0; ni < 2; ni++)
            #pragma unroll
            for (int j = 0; j < 4; j++) {
                int rr = r0 + wm + mi * 16 + (lane >> 4) * 4 + j;
                int qq = q0 + wn + ni * 16 + (lane & 15);
                int b = rr / Ff, fr = rr - b * Ff;
                float g0;
                if (fr < CIN) {
                    size_t s = ((size_t)((t * Bb + b) * CIN + fr)) * Nn + qq;
                    g0 = bf2f(xs_hi[s]) + bf2f(xs_lo[s]);
                } else {
                    size_t s = ((size_t)(b * COUT + fr - CIN)) * Nn + qq;
                    g0 = bf2f(h_hi[s]) + bf2f(h_lo[s]);
                }
                float v = 2.f * acc[mi][ni][j] - g0;
                size_t off = (size_t)rr * Nn + qq;
                u16 hh = f2bf(v);
                g2_hi[off] = hh; g2_lo[off] = f2bf(v - bf2f(hh));
            }
}

// ---------------- K3: fea = Wcat @ G + b ; gates ; LSTM update ----------------
// grid (16 qtiles, 16 b), 256 threads, tile 256(o) x 64(q), K=288 in 9 chunks of 32.
__global__ __launch_bounds__(256) void k_fea(
    int t,
    const u16* __restrict__ Wh, const u16* __restrict__ Wl,
    const u16* __restrict__ xs_hi, const u16* __restrict__ xs_lo,
    u16* __restrict__ h_hi, u16* __restrict__ h_lo,
    const u16* __restrict__ g1_hi, const u16* __restrict__ g1_lo,
    const u16* __restrict__ g2_hi, const u16* __restrict__ g2_lo,
    const float* __restrict__ bias, float* __restrict__ cbuf,
    float* __restrict__ outbuf)
{
    extern __shared__ char smem[];                 // 65536 bytes
    u16 (*WAh)[40] = (u16(*)[40])(smem);           // 256x40x2 = 20480
    u16 (*WAl)[40] = (u16(*)[40])(smem + 20480);   // 20480
    u16 (*BTh)[40] = (u16(*)[40])(smem + 40960);   // 64x40x2 = 5120
    u16 (*BTl)[40] = (u16(*)[40])(smem + 46080);   // 5120
    float (*FEA)[64] = (float(*)[64])(smem);       // union: 256x64x4 = 65536 (used after GEMM)

    const int tid = threadIdx.x, lane = tid & 63, w = tid >> 6;
    const int q0 = blockIdx.x * 64;
    const int b  = blockIdx.y;

    f32x4 acc[4][4];
    #pragma unroll
    for (int i = 0; i < 4; i++)
        #pragma unroll
        for (int j = 0; j < 4; j++) acc[i][j] = (f32x4){0.f, 0.f, 0.f, 0.f};

    for (int c9 = 0; c9 < 9; c9++) {
        int j0 = c9 * 32;
        __syncthreads();
        // stage A (Wcat 256x32 chunk, hi+lo)
        #pragma unroll
        for (int i = 0; i < 4; i++) {
            int lin = (i * 256 + tid) * 8;
            int o = lin >> 5, jj = lin & 31;
            *(short8*)&WAh[o][jj] = *(const short8*)&Wh[(size_t)o * KJ + j0 + jj];
            *(short8*)&WAl[o][jj] = *(const short8*)&Wl[(size_t)o * KJ + j0 + jj];
        }
        // stage B transposed: G rows j0..j0+31, cols q0..q0+63 -> BT[q][j]
        {
            int jl = tid >> 3;
            int j = j0 + jl;
            int ql = (tid & 7) * 8;
            const u16 *sh, *sl; size_t off;
            if (j < Ff) {
                if (j < CIN) { off = ((size_t)((t * Bb + b) * CIN + j)) * Nn; sh = xs_hi; sl = xs_lo; }
                else         { off = ((size_t)(b * COUT + j - CIN)) * Nn;    sh = h_hi;  sl = h_lo; }
            } else if (j < 2 * Ff) { off = ((size_t)(b * Ff + j - Ff)) * Nn;     sh = g1_hi; sl = g1_lo; }
            else                   { off = ((size_t)(b * Ff + j - 2 * Ff)) * Nn; sh = g2_hi; sl = g2_lo; }
            sh += off + q0 + ql; sl += off + q0 + ql;
            short8 vh = *(const short8*)sh;
            short8 vl = *(const short8*)sl;
            #pragma unroll
            for (int m = 0; m < 8; m++) { BTh[ql + m][jl] = (u16)vh[m]; BTl[ql + m][jl] = (u16)vl[m]; }
        }
        __syncthreads();
        const int kb = (lane >> 4) * 8;
        short8 bh[4], bl[4];
        #pragma unroll
        for (int ni = 0; ni < 4; ni++) {
            int col = ni * 16 + (lane & 15);
            bh[ni] = *(const short8*)&BTh[col][kb];
            bl[ni] = *(const short8*)&BTl[col][kb];
        }
        #pragma unroll
        for (int mi = 0; mi < 4; mi++) {
            int row = w * 64 + mi * 16 + (lane & 15);
            short8 ah = *(const short8*)&WAh[row][kb];
            short8 al = *(const short8*)&WAl[row][kb];
            #pragma unroll
            for (int ni = 0; ni < 4; ni++) {
                acc[mi][ni] = __builtin_amdgcn_mfma_f32_16x16x32_bf16(ah, bh[ni], acc[mi][ni], 0, 0, 0);
                acc[mi][ni] = __builtin_amdgcn_mfma_f32_16x16x32_bf16(al, bh[ni], acc[mi][ni], 0, 0, 0);
                acc[mi][ni] = __builtin_amdgcn_mfma_f32_16x16x32_bf16(ah, bl[ni], acc[mi][ni], 0, 0, 0);
            }
        }
    }
    __syncthreads();   // GEMM done; reuse smem as FEA
    #pragma unroll
    for (int mi = 0; mi < 4; mi++)
        #pragma unroll
        for (int ni = 0; ni < 4; ni++)
            #pragma unroll
            for (int j = 0; j < 4; j++) {
                int o = w * 64 + mi * 16 + (lane >> 4) * 4 + j;
                int ql = ni * 16 + (lane & 15);
                FEA[o][ql] = acc[mi][ni][j] + bias[o];
            }
    __syncthreads();
    const int ql = tid & 63;
    const int qg = q0 + ql;
    #pragma unroll
    for (int i = 0; i < 16; i++) {
        int co = (tid >> 6) * 16 + i;
        float iv = FEA[co][ql];
        float jv = FEA[co + 64][ql];
        float fv = FEA[co + 128][ql];
        float ov = FEA[co + 192][ql];
        size_t coff = ((size_t)(b * COUT + co)) * Nn + qg;
        float cc = cbuf[coff];
        float nc = cc * sigm(fv) + sigm(iv) * tanhf(jv);
        float nh = tanhf(nc) * sigm(ov);
        cbuf[coff] = nc;
        u16 hh = f2bf(nh);
        h_hi[coff] = hh; h_lo[coff] = f2bf(nh - bf2f(hh));
        outbuf[(((size_t)t * Bb + b) * COUT + co) * Nn + qg] = nh;
    }
}

// ---------------- P3: outbuf (T,B,CO,N) -> out (B,CO,N,T) ----------------
__global__ __launch_bounds__(256) void k_out_t(const float* __restrict__ outbuf,
                                               float* __restrict__ out) {
    __shared__ float tile[64][65];
    int q0 = blockIdx.x * 64;
    int bo = blockIdx.y;                 // b*COUT + o
    int b = bo >> 6, o = bo & 63;
    int tid = threadIdx.x;
    #pragma unroll
    for (int i = 0; i < 16; i++) {
        int lin = i * 256 + tid;
        int tl = lin >> 6, ql = lin & 63;
        tile[tl][ql] = outbuf[(((size_t)tl * Bb + b) * COUT + o) * Nn + q0 + ql];
    }
    __syncthreads();
    #pragma unroll
    for (int i = 0; i < 16; i++) {
        int lin = i * 256 + tid;
        int ql = lin >> 6, tl = lin & 63;
        out[((size_t)bo * Nn + q0 + ql) * Tt + tl] = tile[tl][ql];
    }
}

extern "C" void kernel_launch(void* const* d_in, const int* in_sizes, int n_in,
                              void* d_out, int out_size, void* d_ws, size_t ws_size,
                              hipStream_t stream)
{
    const float* x    = (const float*)d_in[0];
    const float* adj  = (const float*)d_in[1];
    const float* W    = (const float*)d_in[2];
    const float* bias = (const float*)d_in[3];
    float* out = (float*)d_out;

    size_t off = 0;
    char* base = (char*)d_ws;
    auto take = [&](size_t bytes) -> void* {
        void* r = base + off;
        off += (bytes + 255) & ~(size_t)255;
        return r;
    };
    u16* adj_hi = (u16*)take(2ull * Nn * Nn);
    u16* adj_lo = (u16*)take(2ull * Nn * Nn);
    u16* xs_hi  = (u16*)take(2ull * Tt * Bb * CIN * Nn);
    u16* xs_lo  = (u16*)take(2ull * Tt * Bb * CIN * Nn);
    u16* h_hi   = (u16*)take(2ull * Bb * COUT * Nn);
    u16* h_lo   = (u16*)take(2ull * Bb * COUT * Nn);
    float* cbuf = (float*)take(4ull * Bb * COUT * Nn);
    u16* g1_hi  = (u16*)take(2ull * Bb * Ff * Nn);
    u16* g1_lo  = (u16*)take(2ull * Bb * Ff * Nn);
    u16* g2_hi  = (u16*)take(2ull * Bb * Ff * Nn);
    u16* g2_lo  = (u16*)take(2ull * Bb * Ff * Nn);
    u16* Wc_hi  = (u16*)take(2ull * G4 * KJ);
    u16* Wc_lo  = (u16*)take(2ull * G4 * KJ);
    float* outbuf = (float*)take(4ull * (size_t)Tt * Bb * COUT * Nn);

    if (off > ws_size) {
        // diagnostic: absmax will read back ~ws_size in MB
        float v = (float)(ws_size >> 20);
        k_fill<<<dim3((out_size + 255) / 256), 256, 0, stream>>>(out, out_size, v);
        return;
    }

    hipMemsetAsync(h_hi, 0, 2ull * Bb * COUT * Nn, stream);
    hipMemsetAsync(h_lo, 0, 2ull * Bb * COUT * Nn, stream);
    hipMemsetAsync(cbuf, 0, 4ull * Bb * COUT * Nn, stream);

    k_adj_split<<<dim3((Nn * Nn) / 256), 256, 0, stream>>>(adj, adj_hi, adj_lo);
    k_w_split<<<dim3((G4 * KJ) / 256), 256, 0, stream>>>(W, Wc_hi, Wc_lo);
    k_x_split<<<dim3(Nn / 64, Bb * CIN), 256, 0, stream>>>(x, xs_hi, xs_lo);

    for (int t = 0; t < Tt; t++) {
        k_g1<<<dim3(24, 16), 256, 0, stream>>>(t, xs_hi, xs_lo, h_hi, h_lo,
                                               adj_hi, adj_lo, g1_hi, g1_lo);
        k_g2<<<dim3(24, 16), 256, 0, stream>>>(t, g1_hi, g1_lo, adj_hi, adj_lo,
                                               xs_hi, xs_lo, h_hi, h_lo, g2_hi, g2_lo);
        k_fea<<<dim3(16, 16), 256, 65536, stream>>>(t, Wc_hi, Wc_lo, xs_hi, xs_lo,
                                                    h_hi, h_lo, g1_hi, g1_lo, g2_hi, g2_lo,
                                                    bias, cbuf, outbuf);
    }
    k_out_t<<<dim3(Nn / 64, Bb * COUT), 256, 0, stream>>>(outbuf, out);
}

// Round 2
// 3089.318 us; speedup vs baseline: 2.0112x; 2.0112x over previous
//
#include <hip/hip_runtime.h>
#include <stdint.h>

// ST_BLOCK fused: per step ONE kernel does
//   [g1|g2] = tem @ [adj ; L2]^T   (96x128 per block, K=1024, 3-pass bf16 hi/lo MFMA)
//   fea     = Wcat @ Gq + b        (256x64 per block, K=288, G kept in LDS)
//   LSTM gate update, h/c write.
// L2 = 2*adj@adj - I precomputed once (matches reference's Lap stack exactly).

#define Bb   16
#define CIN  32
#define COUT 64
#define Nn   1024
#define Tt   64
#define Ff   96
#define G4   256
#define KJ   288

#define BUFSZ 57344     // phase-1 staging buffer: A hi/lo 2*12288 + B hi/lo 2*16384
#define GQLO  37888     // Gq_lo offset (64*296*2)
#define GQP   592       // Gq row pitch bytes (296 u16)

typedef unsigned short u16;
typedef short short8 __attribute__((ext_vector_type(8)));
typedef short short4v __attribute__((ext_vector_type(4)));
typedef float f32x4 __attribute__((ext_vector_type(4)));

static __device__ __forceinline__ u16 f2bf(float f) {
    union { float f; uint32_t u; } v; v.f = f;
    uint32_t r = v.u + 0x7FFFu + ((v.u >> 16) & 1u);
    return (u16)(r >> 16);
}
static __device__ __forceinline__ float bf2f(u16 h) {
    union { uint32_t u; float f; } v; v.u = ((uint32_t)h) << 16;
    return v.f;
}
static __device__ __forceinline__ float sigm(float x) { return 1.0f / (1.0f + expf(-x)); }

static __device__ __forceinline__ void gload16(const void* g, void* l) {
    __builtin_amdgcn_global_load_lds(
        (const __attribute__((address_space(1))) void*)g,
        (__attribute__((address_space(3))) void*)l, 16, 0, 0);
}

// ---------------- diagnostics ----------------
__global__ void k_fill(float* out, int n, float v) {
    int i = blockIdx.x * 256 + threadIdx.x;
    if (i < n) out[i] = v;
}

// ---------------- P0: adj -> bcat rows 0..1023 (hi/lo split, [q][n]) ----------------
__global__ __launch_bounds__(256) void k_adj_split(const float* __restrict__ adj,
                                                   u16* __restrict__ hi, u16* __restrict__ lo) {
    int i = blockIdx.x * 256 + threadIdx.x;
    float v = adj[i];
    u16 h = f2bf(v);
    hi[i] = h; lo[i] = f2bf(v - bf2f(h));
}

// ---------------- P0b: adjT split (for L2 GEMM B-side) ----------------
__global__ __launch_bounds__(256) void k_adj_t(const float* __restrict__ adj,
                                               u16* __restrict__ th, u16* __restrict__ tl_) {
    __shared__ float tile[64][65];
    int m0 = blockIdx.x * 64, n0 = blockIdx.y * 64;
    int tid = threadIdx.x;
    #pragma unroll
    for (int i = 0; i < 16; i++) {
        int lin = i * 256 + tid;
        int ml = lin >> 6, nl = lin & 63;
        tile[ml][nl] = adj[(size_t)(m0 + ml) * Nn + n0 + nl];
    }
    __syncthreads();
    #pragma unroll
    for (int i = 0; i < 16; i++) {
        int lin = i * 256 + tid;
        int nl = lin >> 6, ml = lin & 63;
        float v = tile[ml][nl];
        u16 h = f2bf(v);
        size_t off = (size_t)(n0 + nl) * Nn + m0 + ml;
        th[off] = h; tl_[off] = f2bf(v - bf2f(h));
    }
}

// ---------------- P0c: L2[q][n] = 2*sum_m adj[q][m]*adjT[n][m] - I -> bcat rows 1024+ ----------------
__global__ __launch_bounds__(256) void k_l2(
    const u16* __restrict__ a_hi, const u16* __restrict__ a_lo,
    const u16* __restrict__ bt_hi, const u16* __restrict__ bt_lo,
    u16* __restrict__ o_hi, u16* __restrict__ o_lo)
{
    __shared__ u16 Ah[64][40], Al[64][40], Bh[64][40], Bl[64][40];
    const int tid = threadIdx.x, lane = tid & 63, w = tid >> 6;
    const int wm = (w >> 1) * 32, wn = (w & 1) * 32;
    const int r0 = blockIdx.x * 64, q0 = blockIdx.y * 64;
    const int srow = tid >> 2, scol = (tid & 3) * 8;
    const u16* arh = a_hi + (size_t)(r0 + srow) * Nn;
    const u16* arl = a_lo + (size_t)(r0 + srow) * Nn;
    const u16* brh = bt_hi + (size_t)(q0 + srow) * Nn;
    const u16* brl = bt_lo + (size_t)(q0 + srow) * Nn;

    f32x4 acc[2][2];
    #pragma unroll
    for (int i = 0; i < 2; i++)
        #pragma unroll
        for (int j = 0; j < 2; j++) acc[i][j] = (f32x4){0.f, 0.f, 0.f, 0.f};

    for (int k0 = 0; k0 < Nn; k0 += 32) {
        __syncthreads();
        *(short8*)&Ah[srow][scol] = *(const short8*)&arh[k0 + scol];
        *(short8*)&Al[srow][scol] = *(const short8*)&arl[k0 + scol];
        *(short8*)&Bh[srow][scol] = *(const short8*)&brh[k0 + scol];
        *(short8*)&Bl[srow][scol] = *(const short8*)&brl[k0 + scol];
        __syncthreads();
        const int kb = (lane >> 4) * 8;
        short8 ah[2], al[2], bh[2], bl[2];
        #pragma unroll
        for (int mi = 0; mi < 2; mi++) {
            int row = wm + mi * 16 + (lane & 15);
            ah[mi] = *(const short8*)&Ah[row][kb];
            al[mi] = *(const short8*)&Al[row][kb];
        }
        #pragma unroll
        for (int ni = 0; ni < 2; ni++) {
            int col = wn + ni * 16 + (lane & 15);
            bh[ni] = *(const short8*)&Bh[col][kb];
            bl[ni] = *(const short8*)&Bl[col][kb];
        }
        #pragma unroll
        for (int mi = 0; mi < 2; mi++)
            #pragma unroll
            for (int ni = 0; ni < 2; ni++) {
                acc[mi][ni] = __builtin_amdgcn_mfma_f32_16x16x32_bf16(ah[mi], bh[ni], acc[mi][ni], 0, 0, 0);
                acc[mi][ni] = __builtin_amdgcn_mfma_f32_16x16x32_bf16(al[mi], bh[ni], acc[mi][ni], 0, 0, 0);
                acc[mi][ni] = __builtin_amdgcn_mfma_f32_16x16x32_bf16(ah[mi], bl[ni], acc[mi][ni], 0, 0, 0);
            }
    }
    #pragma unroll
    for (int mi = 0; mi < 2; mi++)
        #pragma unroll
        for (int ni = 0; ni < 2; ni++)
            #pragma unroll
            for (int j = 0; j < 4; j++) {
                int rr = r0 + wm + mi * 16 + (lane >> 4) * 4 + j;
                int qq = q0 + wn + ni * 16 + (lane & 15);
                float v = 2.f * acc[mi][ni][j] - ((rr == qq) ? 1.f : 0.f);
                size_t off = (size_t)rr * Nn + qq;
                u16 hh = f2bf(v);
                o_hi[off] = hh; o_lo[off] = f2bf(v - bf2f(hh));
            }
}

// ---------------- P2: W reorder+split: Wcat[o][k*96+f] = W[o][f*3+k] ----------------
__global__ __launch_bounds__(256) void k_w_split(const float* __restrict__ W,
                                                 u16* __restrict__ hi, u16* __restrict__ lo) {
    int idx = blockIdx.x * 256 + threadIdx.x;
    int o = idx / KJ, j = idx - o * KJ;
    int k = j / Ff, f = j - k * Ff;
    float v = W[(size_t)o * KJ + f * 3 + k];
    u16 h = f2bf(v);
    hi[idx] = h; lo[idx] = f2bf(v - bf2f(h));
}

// ---------------- P1: x (B,CIN,N,T) -> xsf (T,B,CIN,N) and xsq (T,B,N,CIN), split ----------------
__global__ __launch_bounds__(256) void k_x_split(const float* __restrict__ x,
        u16* __restrict__ xf_hi, u16* __restrict__ xf_lo,
        u16* __restrict__ xq_hi, u16* __restrict__ xq_lo) {
    __shared__ float tile[64][65];
    int n0 = blockIdx.x * 64;
    int bc = blockIdx.y;
    const float* src = x + (size_t)bc * Nn * Tt;
    int tid = threadIdx.x;
    #pragma unroll
    for (int i = 0; i < 16; i++) {
        int lin = i * 256 + tid;
        int nl = lin >> 6, tl = lin & 63;
        tile[nl][tl] = src[(size_t)(n0 + nl) * Tt + tl];
    }
    __syncthreads();
    int b = bc >> 5, ch = bc & 31;
    #pragma unroll
    for (int i = 0; i < 16; i++) {
        int lin = i * 256 + tid;
        int tl = lin >> 6, nl = lin & 63;
        float v = tile[nl][tl];
        u16 h = f2bf(v), l = f2bf(v - bf2f(h));
        size_t off = (((size_t)tl * Bb + b) * CIN + ch) * Nn + n0 + nl;
        xf_hi[off] = h; xf_lo[off] = l;
        size_t off2 = (((size_t)tl * Bb + b) * Nn + n0 + nl) * CIN + ch;
        xq_hi[off2] = h; xq_lo[off2] = l;
    }
}

// ---------------- K: fused step ----------------
// grid (16 q-tiles, 16 b), 512 threads (8 waves), static LDS 112KB.
__global__ __launch_bounds__(512) void k_step(
    int t,
    const u16* __restrict__ xsf_hi, const u16* __restrict__ xsf_lo,
    const u16* __restrict__ xsq_hi, const u16* __restrict__ xsq_lo,
    u16* __restrict__ hf_hi, u16* __restrict__ hf_lo,
    u16* __restrict__ hq_hi, u16* __restrict__ hq_lo,
    const u16* __restrict__ bcat_hi, const u16* __restrict__ bcat_lo,
    const u16* __restrict__ Wh, const u16* __restrict__ Wl,
    const float* __restrict__ bias, float* __restrict__ cbuf,
    float* __restrict__ outbuf)
{
    __shared__ __attribute__((aligned(16))) char lds[114688];
    const int tid = threadIdx.x, lane = tid & 63, w = tid >> 6;
    const int q0 = blockIdx.x * 64;
    const int bb = blockIdx.y;

    // ----- staging-unit decode: 7 global_load_lds (16B) per thread per chunk -----
    // units: [0,768)=A_hi 96x8, [768,1536)=A_lo, [1536,2560)=B_hi 128x8, [2560,3584)=B_lo
    // LDS dest linear at u*16; SOURCE column-block XOR-swizzled by row (rule #21).
    const u16* srcb[7];
    #pragma unroll
    for (int i = 0; i < 7; i++) {
        int u = (i * 8 + w) * 64 + lane;
        if (u < 1536) {
            int hl = (u >= 768) ? 1 : 0;
            int r = (u - hl * 768) >> 3, c8 = u & 7;
            const u16* p;
            if (r < CIN) p = (hl ? xsf_lo : xsf_hi) + (size_t)((t * Bb + bb) * CIN + r) * Nn;
            else         p = (hl ? hf_lo  : hf_hi ) + (size_t)(bb * COUT + r - CIN) * Nn;
            srcb[i] = p + (c8 ^ (r & 7)) * 8;
        } else {
            int v = u - 1536;
            int hl = v >> 10;
            int r = (v & 1023) >> 3, c8 = v & 7;
            int grow = q0 + r + ((r >= 64) ? (Nn - 64) : 0);   // rows 0..63 adj, 64..127 L2
            srcb[i] = (hl ? bcat_lo : bcat_hi) + (size_t)grow * Nn + (c8 ^ (r & 7)) * 8;
        }
    }

    // ================= phase 1: [g1|g2] = tem @ Bcat^T =================
    const int wr = w >> 2, wc = w & 3;   // 2x4 waves over 96x128
    f32x4 acc[3][2];
    #pragma unroll
    for (int i = 0; i < 3; i++)
        #pragma unroll
        for (int j = 0; j < 2; j++) acc[i][j] = (f32x4){0.f, 0.f, 0.f, 0.f};

    // prologue: issue chunk 0 into buf0
    #pragma unroll
    for (int i = 0; i < 7; i++)
        gload16(srcb[i], lds + (i * 8 + w) * 1024);

    for (int kc = 0; kc < 16; kc++) {
        if (kc < 15) {
            const int nb = ((kc + 1) & 1) * BUFSZ;
            const int k0 = (kc + 1) * 64;
            #pragma unroll
            for (int i = 0; i < 7; i++)
                gload16(srcb[i] + k0, lds + nb + (i * 8 + w) * 1024);
            asm volatile("s_waitcnt vmcnt(7)" ::: "memory");   // chunk kc landed
        } else {
            asm volatile("s_waitcnt vmcnt(0)" ::: "memory");
        }
        __builtin_amdgcn_s_barrier();
        const char* bo = lds + (kc & 1) * BUFSZ;
        #pragma unroll
        for (int kk = 0; kk < 2; kk++) {
            const int ksw = kk * 4 + (lane >> 4);     // 16B-unit index within row
            short8 ah[3], al[3], bh[2], bl[2];
            #pragma unroll
            for (int mi = 0; mi < 3; mi++) {
                int r = wr * 48 + mi * 16 + (lane & 15);
                int off = r * 128 + ((ksw ^ (r & 7)) << 4);
                ah[mi] = *(const short8*)(bo + off);
                al[mi] = *(const short8*)(bo + 12288 + off);
            }
            #pragma unroll
            for (int ni = 0; ni < 2; ni++) {
                int rb = wc * 32 + ni * 16 + (lane & 15);
                int off = 24576 + rb * 128 + ((ksw ^ (rb & 7)) << 4);
                bh[ni] = *(const short8*)(bo + off);
                bl[ni] = *(const short8*)(bo + 16384 + off);
            }
            #pragma unroll
            for (int mi = 0; mi < 3; mi++)
                #pragma unroll
                for (int ni = 0; ni < 2; ni++) {
                    acc[mi][ni] = __builtin_amdgcn_mfma_f32_16x16x32_bf16(ah[mi], bh[ni], acc[mi][ni], 0, 0, 0);
                    acc[mi][ni] = __builtin_amdgcn_mfma_f32_16x16x32_bf16(al[mi], bh[ni], acc[mi][ni], 0, 0, 0);
                    acc[mi][ni] = __builtin_amdgcn_mfma_f32_16x16x32_bf16(ah[mi], bl[ni], acc[mi][ni], 0, 0, 0);
                }
        }
        __builtin_amdgcn_s_barrier();
    }

    // ================= build Gq[64 q][288 j] in LDS (hi at 0, lo at GQLO) =================
    // j 0..31 = x_t (from xsq), 32..95 = h (from hq), 96..191 = g1, 192..287 = g2
    {
        int q = tid >> 3, j4 = (tid & 7) * 4;
        size_t sx = ((size_t)(t * Bb + bb) * Nn + q0 + q) * CIN + j4;
        *(short4v*)(lds + q * GQP + j4 * 2)        = *(const short4v*)&xsq_hi[sx];
        *(short4v*)(lds + GQLO + q * GQP + j4 * 2) = *(const short4v*)&xsq_lo[sx];
    }
    #pragma unroll
    for (int i = 0; i < 2; i++) {
        int u = i * 512 + tid;
        int q = u >> 4, j4 = (u & 15) * 4;
        size_t sh = ((size_t)bb * Nn + q0 + q) * COUT + j4;
        *(short4v*)(lds + q * GQP + (32 + j4) * 2)        = *(const short4v*)&hq_hi[sh];
        *(short4v*)(lds + GQLO + q * GQP + (32 + j4) * 2) = *(const short4v*)&hq_lo[sh];
    }
    #pragma unroll
    for (int mi = 0; mi < 3; mi++)
        #pragma unroll
        for (int ni = 0; ni < 2; ni++) {
            int col = wc * 32 + ni * 16 + (lane & 15);
            int g = col >> 6, ql = col & 63;
            int f0 = wr * 48 + mi * 16 + (lane >> 4) * 4;
            int jd = 96 + g * 96 + f0;
            short4v vh, vl;
            #pragma unroll
            for (int j = 0; j < 4; j++) {
                float v = acc[mi][ni][j];
                u16 hh = f2bf(v);
                vh[j] = (short)hh;
                vl[j] = (short)f2bf(v - bf2f(hh));
            }
            *(short4v*)(lds + ql * GQP + jd * 2) = vh;
            *(short4v*)(lds + GQLO + ql * GQP + jd * 2) = vl;
        }
    __syncthreads();

    // ================= phase 2: fea = Wcat @ Gq^T  (256 o x 64 q, K=288) =================
    // 8 waves x 32 o-rows; A-frags direct from global (W hot in L2), B-frags from LDS.
    f32x4 a2[2][4];
    #pragma unroll
    for (int i = 0; i < 2; i++)
        #pragma unroll
        for (int j = 0; j < 4; j++) a2[i][j] = (f32x4){0.f, 0.f, 0.f, 0.f};

    const int kb8 = (lane >> 4) * 8;
    #pragma unroll
    for (int c = 0; c < 9; c++) {
        int j0 = c * 32;
        short8 wh[2], wl2[2], gh[4], gl[4];
        #pragma unroll
        for (int mi = 0; mi < 2; mi++) {
            int o = w * 32 + mi * 16 + (lane & 15);
            size_t so = (size_t)o * KJ + j0 + kb8;
            wh[mi]  = *(const short8*)&Wh[so];
            wl2[mi] = *(const short8*)&Wl[so];
        }
        #pragma unroll
        for (int ni = 0; ni < 4; ni++) {
            int q = ni * 16 + (lane & 15);
            int off = q * GQP + (j0 + kb8) * 2;
            gh[ni] = *(const short8*)(lds + off);
            gl[ni] = *(const short8*)(lds + GQLO + off);
        }
        #pragma unroll
        for (int mi = 0; mi < 2; mi++)
            #pragma unroll
            for (int ni = 0; ni < 4; ni++) {
                a2[mi][ni] = __builtin_amdgcn_mfma_f32_16x16x32_bf16(wh[mi],  gh[ni], a2[mi][ni], 0, 0, 0);
                a2[mi][ni] = __builtin_amdgcn_mfma_f32_16x16x32_bf16(wl2[mi], gh[ni], a2[mi][ni], 0, 0, 0);
                a2[mi][ni] = __builtin_amdgcn_mfma_f32_16x16x32_bf16(wh[mi],  gl[ni], a2[mi][ni], 0, 0, 0);
            }
    }
    __syncthreads();   // Gq dead; reuse LDS as FEA[q][260 floats]

    #pragma unroll
    for (int mi = 0; mi < 2; mi++) {
        int o0 = w * 32 + mi * 16 + (lane >> 4) * 4;
        f32x4 bv = *(const f32x4*)&bias[o0];
        #pragma unroll
        for (int ni = 0; ni < 4; ni++) {
            int q = ni * 16 + (lane & 15);
            f32x4 v = a2[mi][ni] + bv;
            *(f32x4*)(lds + q * 1040 + o0 * 4) = v;
        }
    }
    __syncthreads();

    // ================= phase 3: LSTM update =================
    {
        const float* FEA = (const float*)lds;
        int q = tid & 63, qg = q0 + q;
        int co0 = (tid >> 6) * 8;
        const float* fr = FEA + q * 260;
        #pragma unroll
        for (int ii = 0; ii < 8; ii++) {
            int co = co0 + ii;
            float iv = fr[co];
            float jv = fr[co + 64];
            float fv = fr[co + 128];
            float ov = fr[co + 192];
            size_t cof = ((size_t)(bb * COUT + co)) * Nn + qg;
            float cc = cbuf[cof];
            float nc = cc * sigm(fv) + sigm(iv) * tanhf(jv);
            float nh = tanhf(nc) * sigm(ov);
            cbuf[cof] = nc;
            u16 hh = f2bf(nh), hl2 = f2bf(nh - bf2f(hh));
            hf_hi[cof] = hh; hf_lo[cof] = hl2;
            size_t hq = ((size_t)bb * Nn + qg) * COUT + co;
            hq_hi[hq] = hh; hq_lo[hq] = hl2;
            outbuf[((size_t)(t * Bb + bb) * COUT + co) * Nn + qg] = nh;
        }
    }
}

// ---------------- P3: outbuf (T,B,CO,N) -> out (B,CO,N,T) ----------------
__global__ __launch_bounds__(256) void k_out_t(const float* __restrict__ outbuf,
                                               float* __restrict__ out) {
    __shared__ float tile[64][65];
    int q0 = blockIdx.x * 64;
    int bo = blockIdx.y;
    int b = bo >> 6, o = bo & 63;
    int tid = threadIdx.x;
    #pragma unroll
    for (int i = 0; i < 16; i++) {
        int lin = i * 256 + tid;
        int tl = lin >> 6, ql = lin & 63;
        tile[tl][ql] = outbuf[(((size_t)tl * Bb + b) * COUT + o) * Nn + q0 + ql];
    }
    __syncthreads();
    #pragma unroll
    for (int i = 0; i < 16; i++) {
        int lin = i * 256 + tid;
        int ql = lin >> 6, tl = lin & 63;
        out[((size_t)bo * Nn + q0 + ql) * Tt + tl] = tile[tl][ql];
    }
}

extern "C" void kernel_launch(void* const* d_in, const int* in_sizes, int n_in,
                              void* d_out, int out_size, void* d_ws, size_t ws_size,
                              hipStream_t stream)
{
    const float* x    = (const float*)d_in[0];
    const float* adj  = (const float*)d_in[1];
    const float* W    = (const float*)d_in[2];
    const float* bias = (const float*)d_in[3];
    float* out = (float*)d_out;

    size_t off = 0;
    char* base = (char*)d_ws;
    auto take = [&](size_t bytes) -> void* {
        void* r = base + off;
        off += (bytes + 255) & ~(size_t)255;
        return r;
    };
    u16* bcat_hi = (u16*)take(2ull * 2 * Nn * Nn);        // rows 0..1023 adj, 1024..2047 L2
    u16* bcat_lo = (u16*)take(2ull * 2 * Nn * Nn);
    u16* adjT_hi = (u16*)take(2ull * Nn * Nn);
    u16* adjT_lo = (u16*)take(2ull * Nn * Nn);
    u16* xsf_hi  = (u16*)take(2ull * Tt * Bb * CIN * Nn);
    u16* xsf_lo  = (u16*)take(2ull * Tt * Bb * CIN * Nn);
    u16* xsq_hi  = (u16*)take(2ull * Tt * Bb * CIN * Nn);
    u16* xsq_lo  = (u16*)take(2ull * Tt * Bb * CIN * Nn);
    u16* hf_hi   = (u16*)take(2ull * Bb * COUT * Nn);
    u16* hf_lo   = (u16*)take(2ull * Bb * COUT * Nn);
    u16* hq_hi   = (u16*)take(2ull * Bb * COUT * Nn);
    u16* hq_lo   = (u16*)take(2ull * Bb * COUT * Nn);
    float* cbuf  = (float*)take(4ull * Bb * COUT * Nn);
    u16* Wc_hi   = (u16*)take(2ull * G4 * KJ);
    u16* Wc_lo   = (u16*)take(2ull * G4 * KJ);
    float* outbuf = (float*)take(4ull * (size_t)Tt * Bb * COUT * Nn);

    if (off > ws_size) {
        float v = (float)(ws_size >> 20);
        k_fill<<<dim3((out_size + 255) / 256), 256, 0, stream>>>(out, out_size, v);
        return;
    }

    hipMemsetAsync(hf_hi, 0, 2ull * Bb * COUT * Nn, stream);
    hipMemsetAsync(hf_lo, 0, 2ull * Bb * COUT * Nn, stream);
    hipMemsetAsync(hq_hi, 0, 2ull * Bb * COUT * Nn, stream);
    hipMemsetAsync(hq_lo, 0, 2ull * Bb * COUT * Nn, stream);
    hipMemsetAsync(cbuf, 0, 4ull * Bb * COUT * Nn, stream);

    k_adj_split<<<dim3((Nn * Nn) / 256), 256, 0, stream>>>(adj, bcat_hi, bcat_lo);
    k_adj_t<<<dim3(16, 16), 256, 0, stream>>>(adj, adjT_hi, adjT_lo);
    k_l2<<<dim3(16, 16), 256, 0, stream>>>(bcat_hi, bcat_lo, adjT_hi, adjT_lo,
                                           bcat_hi + (size_t)Nn * Nn, bcat_lo + (size_t)Nn * Nn);
    k_w_split<<<dim3((G4 * KJ) / 256), 256, 0, stream>>>(W, Wc_hi, Wc_lo);
    k_x_split<<<dim3(Nn / 64, Bb * CIN), 256, 0, stream>>>(x, xsf_hi, xsf_lo, xsq_hi, xsq_lo);

    for (int t = 0; t < Tt; t++) {
        k_step<<<dim3(16, 16), 512, 0, stream>>>(t,
            xsf_hi, xsf_lo, xsq_hi, xsq_lo,
            hf_hi, hf_lo, hq_hi, hq_lo,
            bcat_hi, bcat_lo, Wc_hi, Wc_lo,
            bias, cbuf, outbuf);
    }
    k_out_t<<<dim3(Nn / 64, Bb * COUT), 256, 0, stream>>>(outbuf, out);
}

// Round 4
// 2564.530 us; speedup vs baseline: 2.4228x; 1.2046x over previous
//
#include <hip/hip_runtime.h>
#include <stdint.h>

// ST_BLOCK fused: per step ONE kernel:
//   [g1|g2](96x64) = tem @ [adj;L2]^T slice   (K=1024, 3-pass bf16 hi/lo MFMA)
//   Gq x/h columns captured from the phase-1 A-tile (no xsq/hq side buffers)
//   fea = Wcat @ Gq^T (256 x 32, K=288) ; LSTM update.
// Grid 32 q-tiles x 16 b = 512 blocks, 81920 B LDS -> 2 blocks/CU.
// R3 bug fixed: phase-3 channel decomposition was (tid>>5)*16, ii<16 -> co up to 255,
// writing hf/cbuf/outbuf out of bounds (corrupted W -> NaN). Now (tid>>5)*4, ii<4.

#define Bb   16
#define CIN  32
#define COUT 64
#define Nn   1024
#define Tt   64
#define Ff   96
#define G4   256
#define KJ   288

#define BUFSZ 40960     // A hi/lo 2*12288 + B hi/lo 2*8192
#define GQPB  624       // Gq row pitch bytes (312 u16)
#define GQLO  19968     // Gq_lo offset (32*624)

typedef unsigned short u16;
typedef short short8 __attribute__((ext_vector_type(8)));
typedef short short4v __attribute__((ext_vector_type(4)));
typedef float f32x4 __attribute__((ext_vector_type(4)));

static __device__ __forceinline__ u16 f2bf(float f) {
    union { float f; uint32_t u; } v; v.f = f;
    uint32_t r = v.u + 0x7FFFu + ((v.u >> 16) & 1u);
    return (u16)(r >> 16);
}
static __device__ __forceinline__ float bf2f(u16 h) {
    union { uint32_t u; float f; } v; v.u = ((uint32_t)h) << 16;
    return v.f;
}
static __device__ __forceinline__ float sigm(float x) { return 1.0f / (1.0f + expf(-x)); }

static __device__ __forceinline__ void gload16(const void* g, void* l) {
    __builtin_amdgcn_global_load_lds(
        (const __attribute__((address_space(1))) void*)g,
        (__attribute__((address_space(3))) void*)l, 16, 0, 0);
}

// ---------------- diagnostics ----------------
__global__ void k_fill(float* out, int n, float v) {
    int i = blockIdx.x * 256 + threadIdx.x;
    if (i < n) out[i] = v;
}

// ---------------- P0: adj -> bcat rows 0..1023 ----------------
__global__ __launch_bounds__(256) void k_adj_split(const float* __restrict__ adj,
                                                   u16* __restrict__ hi, u16* __restrict__ lo) {
    int i = blockIdx.x * 256 + threadIdx.x;
    float v = adj[i];
    u16 h = f2bf(v);
    hi[i] = h; lo[i] = f2bf(v - bf2f(h));
}

// ---------------- P0b: adjT split ----------------
__global__ __launch_bounds__(256) void k_adj_t(const float* __restrict__ adj,
                                               u16* __restrict__ th, u16* __restrict__ tl_) {
    __shared__ float tile[64][65];
    int m0 = blockIdx.x * 64, n0 = blockIdx.y * 64;
    int tid = threadIdx.x;
    #pragma unroll
    for (int i = 0; i < 16; i++) {
        int lin = i * 256 + tid;
        int ml = lin >> 6, nl = lin & 63;
        tile[ml][nl] = adj[(size_t)(m0 + ml) * Nn + n0 + nl];
    }
    __syncthreads();
    #pragma unroll
    for (int i = 0; i < 16; i++) {
        int lin = i * 256 + tid;
        int nl = lin >> 6, ml = lin & 63;
        float v = tile[ml][nl];
        u16 h = f2bf(v);
        size_t off = (size_t)(n0 + nl) * Nn + m0 + ml;
        th[off] = h; tl_[off] = f2bf(v - bf2f(h));
    }
}

// ---------------- P0c: L2 = 2*adj@adj - I -> bcat rows 1024+ ----------------
__global__ __launch_bounds__(256) void k_l2(
    const u16* __restrict__ a_hi, const u16* __restrict__ a_lo,
    const u16* __restrict__ bt_hi, const u16* __restrict__ bt_lo,
    u16* __restrict__ o_hi, u16* __restrict__ o_lo)
{
    __shared__ u16 Ah[64][40], Al[64][40], Bh[64][40], Bl[64][40];
    const int tid = threadIdx.x, lane = tid & 63, w = tid >> 6;
    const int wm = (w >> 1) * 32, wn = (w & 1) * 32;
    const int r0 = blockIdx.x * 64, q0 = blockIdx.y * 64;
    const int srow = tid >> 2, scol = (tid & 3) * 8;
    const u16* arh = a_hi + (size_t)(r0 + srow) * Nn;
    const u16* arl = a_lo + (size_t)(r0 + srow) * Nn;
    const u16* brh = bt_hi + (size_t)(q0 + srow) * Nn;
    const u16* brl = bt_lo + (size_t)(q0 + srow) * Nn;

    f32x4 acc[2][2];
    #pragma unroll
    for (int i = 0; i < 2; i++)
        #pragma unroll
        for (int j = 0; j < 2; j++) acc[i][j] = (f32x4){0.f, 0.f, 0.f, 0.f};

    for (int k0 = 0; k0 < Nn; k0 += 32) {
        __syncthreads();
        *(short8*)&Ah[srow][scol] = *(const short8*)&arh[k0 + scol];
        *(short8*)&Al[srow][scol] = *(const short8*)&arl[k0 + scol];
        *(short8*)&Bh[srow][scol] = *(const short8*)&brh[k0 + scol];
        *(short8*)&Bl[srow][scol] = *(const short8*)&brl[k0 + scol];
        __syncthreads();
        const int kb = (lane >> 4) * 8;
        short8 ah[2], al[2], bh[2], bl[2];
        #pragma unroll
        for (int mi = 0; mi < 2; mi++) {
            int row = wm + mi * 16 + (lane & 15);
            ah[mi] = *(const short8*)&Ah[row][kb];
            al[mi] = *(const short8*)&Al[row][kb];
        }
        #pragma unroll
        for (int ni = 0; ni < 2; ni++) {
            int col = wn + ni * 16 + (lane & 15);
            bh[ni] = *(const short8*)&Bh[col][kb];
            bl[ni] = *(const short8*)&Bl[col][kb];
        }
        #pragma unroll
        for (int mi = 0; mi < 2; mi++)
            #pragma unroll
            for (int ni = 0; ni < 2; ni++) {
                acc[mi][ni] = __builtin_amdgcn_mfma_f32_16x16x32_bf16(ah[mi], bh[ni], acc[mi][ni], 0, 0, 0);
                acc[mi][ni] = __builtin_amdgcn_mfma_f32_16x16x32_bf16(al[mi], bh[ni], acc[mi][ni], 0, 0, 0);
                acc[mi][ni] = __builtin_amdgcn_mfma_f32_16x16x32_bf16(ah[mi], bl[ni], acc[mi][ni], 0, 0, 0);
            }
    }
    #pragma unroll
    for (int mi = 0; mi < 2; mi++)
        #pragma unroll
        for (int ni = 0; ni < 2; ni++)
            #pragma unroll
            for (int j = 0; j < 4; j++) {
                int rr = r0 + wm + mi * 16 + (lane >> 4) * 4 + j;
                int qq = q0 + wn + ni * 16 + (lane & 15);
                float v = 2.f * acc[mi][ni][j] - ((rr == qq) ? 1.f : 0.f);
                size_t off = (size_t)rr * Nn + qq;
                u16 hh = f2bf(v);
                o_hi[off] = hh; o_lo[off] = f2bf(v - bf2f(hh));
            }
}

// ---------------- P2: W reorder+split ----------------
__global__ __launch_bounds__(256) void k_w_split(const float* __restrict__ W,
                                                 u16* __restrict__ hi, u16* __restrict__ lo) {
    int idx = blockIdx.x * 256 + threadIdx.x;
    int o = idx / KJ, j = idx - o * KJ;
    int k = j / Ff, f = j - k * Ff;
    float v = W[(size_t)o * KJ + f * 3 + k];
    u16 h = f2bf(v);
    hi[idx] = h; lo[idx] = f2bf(v - bf2f(h));
}

// ---------------- P1: x (B,CIN,N,T) -> xsf (T,B,CIN,N) split ----------------
__global__ __launch_bounds__(256) void k_x_split(const float* __restrict__ x,
        u16* __restrict__ xf_hi, u16* __restrict__ xf_lo) {
    __shared__ float tile[64][65];
    int n0 = blockIdx.x * 64;
    int bc = blockIdx.y;
    const float* src = x + (size_t)bc * Nn * Tt;
    int tid = threadIdx.x;
    #pragma unroll
    for (int i = 0; i < 16; i++) {
        int lin = i * 256 + tid;
        int nl = lin >> 6, tl = lin & 63;
        tile[nl][tl] = src[(size_t)(n0 + nl) * Tt + tl];
    }
    __syncthreads();
    int b = bc >> 5, ch = bc & 31;
    #pragma unroll
    for (int i = 0; i < 16; i++) {
        int lin = i * 256 + tid;
        int tl = lin >> 6, nl = lin & 63;
        float v = tile[nl][tl];
        u16 h = f2bf(v), l = f2bf(v - bf2f(h));
        size_t off = (((size_t)tl * Bb + b) * CIN + ch) * Nn + n0 + nl;
        xf_hi[off] = h; xf_lo[off] = l;
    }
}

// ---------------- K: fused step ----------------
// grid (32 q-tiles, 16 b), 512 threads, LDS 81920 -> 2 blocks/CU.
__global__ __launch_bounds__(512, 4) void k_step(
    int t,
    const u16* __restrict__ xsf_hi, const u16* __restrict__ xsf_lo,
    u16* __restrict__ hf_hi, u16* __restrict__ hf_lo,
    const u16* __restrict__ bcat_hi, const u16* __restrict__ bcat_lo,
    const u16* __restrict__ Wh, const u16* __restrict__ Wl,
    const float* __restrict__ bias, float* __restrict__ cbuf,
    float* __restrict__ outbuf)
{
    __shared__ __attribute__((aligned(16))) char lds[81920];
    const int tid = threadIdx.x, lane = tid & 63, w = tid >> 6;
    const int bx = blockIdx.x;           // q-tile (32 wide)
    const int q0g = bx * 32;
    const int bb = blockIdx.y;

    // ----- staging decode: 5 x 16B global_load_lds per thread per chunk -----
    // units: [0,768)=A_hi 96x8, [768,1536)=A_lo, [1536,2048)=B_hi 64x8, [2048,2560)=B_lo
    // LDS dest linear; SOURCE 16B-unit index XOR-swizzled by row (both-sides rule).
    const u16* srcb[5];
    #pragma unroll
    for (int i = 0; i < 5; i++) {
        int u = i * 512 + tid;
        if (u < 1536) {
            int hl = (u >= 768) ? 1 : 0;
            int r = (u - hl * 768) >> 3, c8 = u & 7;
            const u16* p;
            if (r < CIN) p = (hl ? xsf_lo : xsf_hi) + (size_t)((t * Bb + bb) * CIN + r) * Nn;
            else         p = (hl ? hf_lo  : hf_hi ) + (size_t)(bb * COUT + r - CIN) * Nn;
            srcb[i] = p + (c8 ^ (r & 7)) * 8;
        } else {
            int v = u - 1536;
            int hl = v >> 9;
            int r = (v & 511) >> 3, c8 = v & 7;
            int grow = q0g + (r & 31) + ((r >= 32) ? Nn : 0);   // 0..31 adj, 32..63 L2
            srcb[i] = (hl ? bcat_lo : bcat_hi) + (size_t)grow * Nn + (c8 ^ (r & 7)) * 8;
        }
    }

    // ================= phase 1: [g1|g2] = tem @ Bcat^T (96 x 64) =================
    const int wr = w >> 2, wc = w & 3;   // 2x4 waves: rows wr*48+mi*16, cols wc*16
    f32x4 acc[3];
    #pragma unroll
    for (int i = 0; i < 3; i++) acc[i] = (f32x4){0.f, 0.f, 0.f, 0.f};

    u16 cxh[6], cxl[6];
    #pragma unroll
    for (int i = 0; i < 6; i++) { cxh[i] = 0; cxl[i] = 0; }
    const int capkc = bx >> 1;

    // prologue: chunk 0 -> buf0
    #pragma unroll
    for (int i = 0; i < 5; i++)
        gload16(srcb[i], lds + (i * 512 + tid) * 16);

    for (int kc = 0; kc < 16; kc++) {
        if (kc < 15) {
            char* nb = lds + ((kc + 1) & 1) * BUFSZ;
            const int k0 = (kc + 1) * 64;
            #pragma unroll
            for (int i = 0; i < 5; i++)
                gload16(srcb[i] + k0, nb + (i * 512 + tid) * 16);
            asm volatile("s_waitcnt vmcnt(5)" ::: "memory");
        } else {
            asm volatile("s_waitcnt vmcnt(0)" ::: "memory");
        }
        __builtin_amdgcn_s_barrier();
        const char* bo = lds + (kc & 1) * BUFSZ;
        #pragma unroll
        for (int kk = 0; kk < 2; kk++) {
            const int ksw = kk * 4 + (lane >> 4);
            short8 ah[3], al[3], bh, bl;
            #pragma unroll
            for (int mi = 0; mi < 3; mi++) {
                int r = wr * 48 + mi * 16 + (lane & 15);
                int off = r * 128 + ((ksw ^ (r & 7)) << 4);
                ah[mi] = *(const short8*)(bo + off);
                al[mi] = *(const short8*)(bo + 12288 + off);
            }
            {
                int rb = wc * 16 + (lane & 15);
                int off = 24576 + rb * 128 + ((ksw ^ (rb & 7)) << 4);
                bh = *(const short8*)(bo + off);
                bl = *(const short8*)(bo + 8192 + off);
            }
            #pragma unroll
            for (int mi = 0; mi < 3; mi++) {
                acc[mi] = __builtin_amdgcn_mfma_f32_16x16x32_bf16(ah[mi], bh, acc[mi], 0, 0, 0);
                acc[mi] = __builtin_amdgcn_mfma_f32_16x16x32_bf16(al[mi], bh, acc[mi], 0, 0, 0);
                acc[mi] = __builtin_amdgcn_mfma_f32_16x16x32_bf16(ah[mi], bl, acc[mi], 0, 0, 0);
            }
        }
        if (kc == capkc) {
            // A-tile cols q0g..q0g+31 ARE tem[f][q]: capture Gq x/h part to regs.
            int q = lane & 31;
            int jg = (w << 1) | (lane >> 5);
            int lc = ((bx & 1) << 5) | q;
            int u8 = lc >> 3, byoff = (lc & 7) * 2;
            #pragma unroll
            for (int jj = 0; jj < 6; jj++) {
                int j = jg * 6 + jj;
                int off = j * 128 + (((u8) ^ (j & 7)) << 4) + byoff;
                cxh[jj] = *(const u16*)(bo + off);
                cxl[jj] = *(const u16*)(bo + 12288 + off);
            }
            asm volatile("s_waitcnt lgkmcnt(0)" ::: "memory");
            __builtin_amdgcn_sched_barrier(0);
        }
        __builtin_amdgcn_s_barrier();
    }

    // ================= build Gq[32 q][288 j] (hi at 0, lo at GQLO) =================
    {
        int q = lane & 31;
        int jg = (w << 1) | (lane >> 5);
        #pragma unroll
        for (int jj = 0; jj < 6; jj++) {
            int j = jg * 6 + jj;
            *(u16*)(lds + q * GQPB + j * 2) = cxh[jj];
            *(u16*)(lds + GQLO + q * GQPB + j * 2) = cxl[jj];
        }
    }
    #pragma unroll
    for (int mi = 0; mi < 3; mi++) {
        int c = wc * 16 + (lane & 15);
        int g = c >> 5, ql = c & 31;
        int f0 = wr * 48 + mi * 16 + (lane >> 4) * 4;
        int jd = 96 + g * 96 + f0;
        short4v vh, vl;
        #pragma unroll
        for (int j = 0; j < 4; j++) {
            float v = acc[mi][j];
            u16 hh = f2bf(v);
            vh[j] = (short)hh;
            vl[j] = (short)f2bf(v - bf2f(hh));
        }
        *(short4v*)(lds + ql * GQPB + jd * 2) = vh;
        *(short4v*)(lds + GQLO + ql * GQPB + jd * 2) = vl;
    }
    __syncthreads();

    // ================= phase 2: fea = Wcat @ Gq^T (256 o x 32 q, K=288) =================
    f32x4 a2[2][2];
    #pragma unroll
    for (int i = 0; i < 2; i++)
        #pragma unroll
        for (int j = 0; j < 2; j++) a2[i][j] = (f32x4){0.f, 0.f, 0.f, 0.f};

    const int kb8 = (lane >> 4) * 8;
    #pragma unroll
    for (int c = 0; c < 9; c++) {
        int j0 = c * 32;
        short8 wh[2], wl2[2], gh[2], gl[2];
        #pragma unroll
        for (int mi = 0; mi < 2; mi++) {
            int o = w * 32 + mi * 16 + (lane & 15);
            size_t so = (size_t)o * KJ + j0 + kb8;
            wh[mi]  = *(const short8*)&Wh[so];
            wl2[mi] = *(const short8*)&Wl[so];
        }
        #pragma unroll
        for (int ni = 0; ni < 2; ni++) {
            int q = ni * 16 + (lane & 15);
            int off = q * GQPB + (j0 + kb8) * 2;
            gh[ni] = *(const short8*)(lds + off);
            gl[ni] = *(const short8*)(lds + GQLO + off);
        }
        #pragma unroll
        for (int mi = 0; mi < 2; mi++)
            #pragma unroll
            for (int ni = 0; ni < 2; ni++) {
                a2[mi][ni] = __builtin_amdgcn_mfma_f32_16x16x32_bf16(wh[mi],  gh[ni], a2[mi][ni], 0, 0, 0);
                a2[mi][ni] = __builtin_amdgcn_mfma_f32_16x16x32_bf16(wl2[mi], gh[ni], a2[mi][ni], 0, 0, 0);
                a2[mi][ni] = __builtin_amdgcn_mfma_f32_16x16x32_bf16(wh[mi],  gl[ni], a2[mi][ni], 0, 0, 0);
            }
    }
    __syncthreads();   // Gq dead; reuse LDS as FEA[o][33 floats]

    {
        float* FEAf = (float*)lds;
        #pragma unroll
        for (int mi = 0; mi < 2; mi++) {
            int o0 = w * 32 + mi * 16 + (lane >> 4) * 4;
            f32x4 bv = *(const f32x4*)&bias[o0];
            #pragma unroll
            for (int ni = 0; ni < 2; ni++) {
                int q = ni * 16 + (lane & 15);
                #pragma unroll
                for (int j = 0; j < 4; j++)
                    FEAf[(o0 + j) * 33 + q] = a2[mi][ni][j] + bv[j];
            }
        }
    }
    __syncthreads();

    // ================= phase 3: LSTM update =================
    // 512 threads: q = tid&31 (32 cols), group = tid>>5 (16 groups) x 4 channels = 64.
    {
        const float* FEAf = (const float*)lds;
        int q = tid & 31, qg = q0g + q;
        int co0 = (tid >> 5) * 4;
        #pragma unroll
        for (int ii = 0; ii < 4; ii++) {
            int co = co0 + ii;
            float iv = FEAf[co * 33 + q];
            float jv = FEAf[(co + 64) * 33 + q];
            float fv = FEAf[(co + 128) * 33 + q];
            float ov = FEAf[(co + 192) * 33 + q];
            size_t cof = ((size_t)(bb * COUT + co)) * Nn + qg;
            float cc = cbuf[cof];
            float nc = cc * sigm(fv) + sigm(iv) * tanhf(jv);
            float nh = tanhf(nc) * sigm(ov);
            cbuf[cof] = nc;
            u16 hh = f2bf(nh);
            hf_hi[cof] = hh; hf_lo[cof] = f2bf(nh - bf2f(hh));
            outbuf[((size_t)(t * Bb + bb) * COUT + co) * Nn + qg] = nh;
        }
    }
}

// ---------------- P3: outbuf (T,B,CO,N) -> out (B,CO,N,T) ----------------
__global__ __launch_bounds__(256) void k_out_t(const float* __restrict__ outbuf,
                                               float* __restrict__ out) {
    __shared__ float tile[64][65];
    int q0 = blockIdx.x * 64;
    int bo = blockIdx.y;
    int b = bo >> 6, o = bo & 63;
    int tid = threadIdx.x;
    #pragma unroll
    for (int i = 0; i < 16; i++) {
        int lin = i * 256 + tid;
        int tl = lin >> 6, ql = lin & 63;
        tile[tl][ql] = outbuf[(((size_t)tl * Bb + b) * COUT + o) * Nn + q0 + ql];
    }
    __syncthreads();
    #pragma unroll
    for (int i = 0; i < 16; i++) {
        int lin = i * 256 + tid;
        int ql = lin >> 6, tl = lin & 63;
        out[((size_t)bo * Nn + q0 + ql) * Tt + tl] = tile[tl][ql];
    }
}

extern "C" void kernel_launch(void* const* d_in, const int* in_sizes, int n_in,
                              void* d_out, int out_size, void* d_ws, size_t ws_size,
                              hipStream_t stream)
{
    const float* x    = (const float*)d_in[0];
    const float* adj  = (const float*)d_in[1];
    const float* W    = (const float*)d_in[2];
    const float* bias = (const float*)d_in[3];
    float* out = (float*)d_out;

    size_t off = 0;
    char* base = (char*)d_ws;
    auto take = [&](size_t bytes) -> void* {
        void* r = base + off;
        off += (bytes + 255) & ~(size_t)255;
        return r;
    };
    u16* bcat_hi = (u16*)take(2ull * 2 * Nn * Nn);
    u16* bcat_lo = (u16*)take(2ull * 2 * Nn * Nn);
    u16* adjT_hi = (u16*)take(2ull * Nn * Nn);
    u16* adjT_lo = (u16*)take(2ull * Nn * Nn);
    u16* xsf_hi  = (u16*)take(2ull * Tt * Bb * CIN * Nn);
    u16* xsf_lo  = (u16*)take(2ull * Tt * Bb * CIN * Nn);
    u16* hf_hi   = (u16*)take(2ull * Bb * COUT * Nn);
    u16* hf_lo   = (u16*)take(2ull * Bb * COUT * Nn);
    float* cbuf  = (float*)take(4ull * Bb * COUT * Nn);
    u16* Wc_hi   = (u16*)take(2ull * G4 * KJ);
    u16* Wc_lo   = (u16*)take(2ull * G4 * KJ);
    float* outbuf = (float*)take(4ull * (size_t)Tt * Bb * COUT * Nn);

    if (off > ws_size) {
        float v = (float)(ws_size >> 20);
        k_fill<<<dim3((out_size + 255) / 256), 256, 0, stream>>>(out, out_size, v);
        return;
    }

    hipMemsetAsync(hf_hi, 0, 2ull * Bb * COUT * Nn, stream);
    hipMemsetAsync(hf_lo, 0, 2ull * Bb * COUT * Nn, stream);
    hipMemsetAsync(cbuf, 0, 4ull * Bb * COUT * Nn, stream);

    k_adj_split<<<dim3((Nn * Nn) / 256), 256, 0, stream>>>(adj, bcat_hi, bcat_lo);
    k_adj_t<<<dim3(16, 16), 256, 0, stream>>>(adj, adjT_hi, adjT_lo);
    k_l2<<<dim3(16, 16), 256, 0, stream>>>(bcat_hi, bcat_lo, adjT_hi, adjT_lo,
                                           bcat_hi + (size_t)Nn * Nn, bcat_lo + (size_t)Nn * Nn);
    k_w_split<<<dim3((G4 * KJ) / 256), 256, 0, stream>>>(W, Wc_hi, Wc_lo);
    k_x_split<<<dim3(Nn / 64, Bb * CIN), 256, 0, stream>>>(x, xsf_hi, xsf_lo);

    for (int t = 0; t < Tt; t++) {
        k_step<<<dim3(32, 16), 512, 0, stream>>>(t,
            xsf_hi, xsf_lo, hf_hi, hf_lo,
            bcat_hi, bcat_lo, Wc_hi, Wc_lo,
            bias, cbuf, outbuf);
    }
    k_out_t<<<dim3(Nn / 64, Bb * COUT), 256, 0, stream>>>(outbuf, out);
}